// Round 17
// baseline (212.491 us; speedup 1.0000x reference)
//
#include <hip/hip_runtime.h>
#include <cstddef>

// SASRec inference. Round 17: MEASUREMENT — k_layers launched TWICE
// (idempotent: const inputs -> Eh/El, state is LDS-local). L(k_layers) =
// total - 154.9us settles whether k_layers is ~74us (attribution) or ~20us
// (phase model). k_packw / k_layers body / k_score byte-identical to R16.

#define NITEMS 200000
#define Bsz 512
#define Ssz 64
#define Dsz 64
#define EPSV 1e-3f
#define NEGV (-4294967295.0f)   // -2^32 + 1

typedef __attribute__((ext_vector_type(8))) short short8;   // 8 bf16
typedef __attribute__((ext_vector_type(4))) float f32x4;
typedef unsigned short ushort_t;
typedef unsigned long long u64_t;

static __device__ __forceinline__ float wsum(float v){
#pragma unroll
  for (int o = 32; o > 0; o >>= 1) v += __shfl_xor(v, o, 64);
  return v;
}
static __device__ __forceinline__ float wmax(float v){
#pragma unroll
  for (int o = 32; o > 0; o >>= 1) v = fmaxf(v, __shfl_xor(v, o, 64));
  return v;
}

// bf16 round-to-nearest-even (finite inputs only)
static __device__ __forceinline__ ushort_t f2b(float f){
  unsigned u = __float_as_uint(f);
  unsigned r = u + 0x7fffu + ((u >> 16) & 1u);
  return (ushort_t)(r >> 16);
}
static __device__ __forceinline__ float b2f(ushort_t h){
  return __uint_as_float(((unsigned)h) << 16);
}

// 8 consecutive f32 -> bf16 hi/lo fragments (in registers)
static __device__ __forceinline__ void a_frag(const float* __restrict__ p,
    short8& h8, short8& l8){
  float4 v0 = *(const float4*)p, v1 = *(const float4*)(p + 4);
  float f[8] = {v0.x,v0.y,v0.z,v0.w,v1.x,v1.y,v1.z,v1.w};
#pragma unroll
  for (int j = 0; j < 8; ++j){
    ushort_t hh = f2b(f[j]);
    h8[j] = (short)hh;
    l8[j] = (short)f2b(f[j] - b2f(hh));
  }
}

// ----------------------------------------------------------- weight pack ----
__global__ __launch_bounds__(512) void k_packw(const float* __restrict__ Wq,
    const float* __restrict__ Wk, const float* __restrict__ Wv,
    const float* __restrict__ W1, const float* __restrict__ W2,
    short8* __restrict__ Wp){
  const int m = blockIdx.x;            // 0..9
  const int l = m / 5, which = m % 5;
  const float* Ws[5] = {Wq, Wk, Wv, W1, W2};
  const float* Wg = Ws[which] + l * 4096;
  const int t = threadIdx.x;
  const int lane = t & 63, s = t >> 6;           // s = 0..7
  const int li = lane & 15, g = lane >> 4;
  const int cb = s >> 1, kc = s & 1;
  short8 h, lo;
#pragma unroll
  for (int j = 0; j < 8; ++j){
    float f = Wg[(kc*32 + g*8 + j)*64 + cb*16 + li];
    ushort_t hh = f2b(f);
    h[j] = (short)hh;
    lo[j] = (short)f2b(f - b2f(hh));
  }
  Wp[(m*16 + s)*64 + lane] = h;
  Wp[(m*16 + 8 + s)*64 + lane] = lo;
}

// 2-tile GEMM strip vs PACKED weight frags (8 coalesced 16B loads + MFMA)
static __device__ __forceinline__ void mmW2p(const short8 ah[2], const short8 al[2],
    const short8* __restrict__ Wp, int m, int cbh, int lane, f32x4 acc[2]){
#pragma unroll
  for (int nt = 0; nt < 2; ++nt){
    acc[nt] = (f32x4)(0.f);
#pragma unroll
    for (int kc = 0; kc < 2; ++kc){
      int s = (cbh*2 + nt)*2 + kc;
      short8 bh = Wp[(m*16 + s)*64 + lane];
      short8 bl = Wp[(m*16 + 8 + s)*64 + lane];
      acc[nt] = __builtin_amdgcn_mfma_f32_16x16x32_bf16(ah[kc], bh, acc[nt], 0, 0, 0);
      acc[nt] = __builtin_amdgcn_mfma_f32_16x16x32_bf16(ah[kc], bl, acc[nt], 0, 0, 0);
      acc[nt] = __builtin_amdgcn_mfma_f32_16x16x32_bf16(al[kc], bh, acc[nt], 0, 0, 0);
    }
  }
}

// 2-tile GEMM strip: A-frags in registers, B rows from f32 LDS ([n][k] layout)
static __device__ __forceinline__ void mmB2(const short8 ah[2], const short8 al[2],
    const float (*__restrict__ B)[68], int cbh, int li, int g, f32x4 acc[2]){
#pragma unroll
  for (int nt = 0; nt < 2; ++nt){
    acc[nt] = (f32x4)(0.f);
#pragma unroll
    for (int kc = 0; kc < 2; ++kc){
      short8 bh, bl;
      a_frag(&B[cbh*32 + nt*16 + li][kc*32 + g*8], bh, bl);
      acc[nt] = __builtin_amdgcn_mfma_f32_16x16x32_bf16(ah[kc], bh, acc[nt], 0, 0, 0);
      acc[nt] = __builtin_amdgcn_mfma_f32_16x16x32_bf16(ah[kc], bl, acc[nt], 0, 0, 0);
      acc[nt] = __builtin_amdgcn_mfma_f32_16x16x32_bf16(al[kc], bh, acc[nt], 0, 0, 0);
    }
  }
}

// ------------------------------------------------------ fused block layers --
__global__ __launch_bounds__(512, 4) void k_layers(const int* __restrict__ ids,
    const float* __restrict__ item_emb, const float* __restrict__ pos_emb,
    const float* __restrict__ ln1g, const float* __restrict__ ln1b,
    const short8* __restrict__ Wp,
    const float* __restrict__ bq, const float* __restrict__ bk,
    const float* __restrict__ bv,
    const float* __restrict__ ln2g, const float* __restrict__ ln2b,
    const float* __restrict__ b1, const float* __restrict__ b2,
    const float* __restrict__ lnfg, const float* __restrict__ lnfb,
    ushort_t* __restrict__ Eh, ushort_t* __restrict__ El){
  __shared__ float B0[64][68];   // seq -> V^T -> (next) seq
  __shared__ float B1[64][68];   // xq (LN1 out) -> res (LN2 out)
  __shared__ float B2[64][68];   // Q -> scores/P -> FFN hidden
  __shared__ float B3[64][68];   // K -> x (attn+residual)

  const int t = threadIdx.x;
  const int lane = t & 63, wid = t >> 6;        // 8 waves
  const int li = lane & 15, g = lane >> 4;
  const int qb = wid & 3, cbh = wid >> 2;       // rows qb*16.., cols cbh*32..+31
  const int b = blockIdx.x;

  // ---- phase 0 (fused embed): gather + pos -> B0 (f32); ballot mask ----
#pragma unroll
  for (int it = 0; it < 2; ++it){
    int e4 = t + 512 * it;
    int r = e4 >> 4, c4 = e4 & 15, c = c4 * 4;
    int id = ids[b * Ssz + r];
    float4 v = make_float4(0.f, 0.f, 0.f, 0.f);
    if (id != NITEMS){
      float4 a = ((const float4*)(item_emb + (size_t)id * 64))[c4];
      float4 p = ((const float4*)(pos_emb + r * 64))[c4];
      v = make_float4(a.x + p.x, a.y + p.y, a.z + p.z, a.w + p.w);
    }
    *(float4*)&B0[r][c] = v;
  }
  const int myid = ids[b * Ssz + lane];
  const u64_t mvec = __ballot(myid != NITEMS);   // bit r = row r valid

  for (int l = 0; l < 2; ++l){
    const int mb = l * 5;
    __syncthreads();   // fences phase-0 (l=0) / previous layer-out (l=1)

    // ---- LN1: B0 -> B1 (8 rows/wave) ----
    for (int r = wid; r < 64; r += 8){
      float x = B0[r][lane];
      float mu = wsum(x) * (1.f / 64.f);
      float dv = x - mu;
      float var = wsum(dv * dv) * (1.f / 64.f);
      B1[r][lane] = dv * (1.f / sqrtf(var + EPSV)) * ln1g[l*64 + lane] + ln1b[l*64 + lane];
    }
    __syncthreads();

    // ---- ph1: A-frags of seq (B0) and LN1 (B1); Q -> B2, K -> B3 ----
    short8 a0h[2], a0l[2], a1h[2], a1l[2];
#pragma unroll
    for (int kc = 0; kc < 2; ++kc){
      a_frag(&B0[qb*16 + li][kc*32 + g*8], a0h[kc], a0l[kc]);
      a_frag(&B1[qb*16 + li][kc*32 + g*8], a1h[kc], a1l[kc]);
    }
    { f32x4 acc[2]; mmW2p(a1h, a1l, Wp, mb + 0, cbh, lane, acc);
#pragma unroll
      for (int nt = 0; nt < 2; ++nt){
        int col = cbh*32 + nt*16 + li; float bb = bq[l*64 + col];
#pragma unroll
        for (int r4 = 0; r4 < 4; ++r4) B2[qb*16 + g*4 + r4][col] = acc[nt][r4] + bb;
      }
    }
    { f32x4 acc[2]; mmW2p(a0h, a0l, Wp, mb + 1, cbh, lane, acc);
#pragma unroll
      for (int nt = 0; nt < 2; ++nt){
        int col = cbh*32 + nt*16 + li; float bb = bk[l*64 + col];
#pragma unroll
        for (int r4 = 0; r4 < 4; ++r4) B3[qb*16 + g*4 + r4][col] = acc[nt][r4] + bb;
      }
    }
    __syncthreads();

    // ---- ph2: V (from seq frags) -> B0 transposed; snapshot Q frags ----
    { f32x4 acc[2]; mmW2p(a0h, a0l, Wp, mb + 2, cbh, lane, acc);
#pragma unroll
      for (int nt = 0; nt < 2; ++nt){
        int col = cbh*32 + nt*16 + li; float bb = bv[l*64 + col];
#pragma unroll
        for (int r4 = 0; r4 < 4; ++r4) B0[col][qb*16 + g*4 + r4] = acc[nt][r4] + bb;
      }
    }
    short8 qh[2], ql[2];
#pragma unroll
    for (int kc = 0; kc < 2; ++kc)
      a_frag(&B2[qb*16 + li][kc*32 + g*8], qh[kc], ql[kc]);
    __syncthreads();

    // ---- ph3: scores = Q @ K^T -> B2 (Q dead, snapshotted) ----
    { f32x4 acc[2]; mmB2(qh, ql, B3, cbh, li, g, acc);
#pragma unroll
      for (int nt = 0; nt < 2; ++nt){
        int col = cbh*32 + nt*16 + li;
#pragma unroll
        for (int r4 = 0; r4 < 4; ++r4) B2[qb*16 + g*4 + r4][col] = acc[nt][r4];
      }
    }
    __syncthreads();

    // ---- ph4: masked softmax in place (B2) ----
    for (int r = wid; r < 64; r += 8){
      float raw = B2[r][lane];
      bool valid = (lane <= r) && ((mvec >> lane) & 1);
      float sc = valid ? raw * 0.125f : NEGV;
      float m = wmax(sc);
      float e = __expf(sc - m);
      float ssumv = wsum(e);
      float qm = ((mvec >> r) & 1) ? 1.f : 0.f;
      B2[r][lane] = (e / ssumv) * qm;
    }
    __syncthreads();

    // ---- ph5: x = P @ V + xq -> B3 (K dead) ----
    { short8 pfh[2], pfl[2];
#pragma unroll
      for (int kc = 0; kc < 2; ++kc)
        a_frag(&B2[qb*16 + li][kc*32 + g*8], pfh[kc], pfl[kc]);
      f32x4 acc[2]; mmB2(pfh, pfl, B0, cbh, li, g, acc);
#pragma unroll
      for (int nt = 0; nt < 2; ++nt){
        int col = cbh*32 + nt*16 + li;
#pragma unroll
        for (int r4 = 0; r4 < 4; ++r4){
          int row = qb*16 + g*4 + r4;
          B3[row][col] = acc[nt][r4] + B1[row][col];
        }
      }
    }
    __syncthreads();

    // ---- ph6: LN2: B3 -> B1 (xq dead) ----
    for (int r = wid; r < 64; r += 8){
      float x = B3[r][lane];
      float mu = wsum(x) * (1.f / 64.f);
      float dv = x - mu;
      float var = wsum(dv * dv) * (1.f / 64.f);
      B1[r][lane] = dv * (1.f / sqrtf(var + EPSV)) * ln2g[l*64 + lane] + ln2b[l*64 + lane];
    }
    __syncthreads();

    // ---- ph7: h = relu(res @ W1 + b1) -> B2 (P dead) ----
    { short8 rh[2], rl[2];
#pragma unroll
      for (int kc = 0; kc < 2; ++kc)
        a_frag(&B1[qb*16 + li][kc*32 + g*8], rh[kc], rl[kc]);
      f32x4 acc[2]; mmW2p(rh, rl, Wp, mb + 3, cbh, lane, acc);
#pragma unroll
      for (int nt = 0; nt < 2; ++nt){
        int col = cbh*32 + nt*16 + li; float bb = b1[l*64 + col];
#pragma unroll
        for (int r4 = 0; r4 < 4; ++r4)
          B2[qb*16 + g*4 + r4][col] = fmaxf(acc[nt][r4] + bb, 0.f);
      }
    }
    __syncthreads();

    // ---- ph8: out = (h @ W2 + b2 + res) * mask -> B0 (V^T dead) ----
    { short8 hh[2], hl[2];
#pragma unroll
      for (int kc = 0; kc < 2; ++kc)
        a_frag(&B2[qb*16 + li][kc*32 + g*8], hh[kc], hl[kc]);
      f32x4 acc[2]; mmW2p(hh, hl, Wp, mb + 4, cbh, lane, acc);
#pragma unroll
      for (int nt = 0; nt < 2; ++nt){
        int col = cbh*32 + nt*16 + li; float bb = b2[l*64 + col];
#pragma unroll
        for (int r4 = 0; r4 < 4; ++r4){
          int row = qb*16 + g*4 + r4;
          float m = ((mvec >> row) & 1) ? 1.f : 0.f;
          B0[row][col] = (acc[nt][r4] + bb + B1[row][col]) * m;
        }
      }
    }
  }

  // ---- fused final LN on row 63 -> packed bf16 hi/lo E ----
  __syncthreads();
  if (wid == 0){
    float x = B0[63][lane];
    float mu = wsum(x) * (1.f / 64.f);
    float dv = x - mu;
    float var = wsum(dv * dv) * (1.f / 64.f);
    float o = dv * (1.f / sqrtf(var + EPSV)) * lnfg[lane] + lnfb[lane];
    ushort_t h = f2b(o);
    Eh[b * 64 + lane] = h;
    El[b * 64 + lane] = f2b(o - b2f(h));
  }
}

// --------------------------------------------------------------- scoring ---
// R16 kernel: contiguous 256B NT stores (write-allocate elided).
#define LOADA(DH, DL, c) { int er = (c)*64 + w*16 + li;                 \
  DH[0] = *(const short8*)&Eh[er*64 + g*8];                             \
  DH[1] = *(const short8*)&Eh[er*64 + 32 + g*8];                        \
  DL[0] = *(const short8*)&El[er*64 + g*8];                             \
  DL[1] = *(const short8*)&El[er*64 + 32 + g*8]; }

#define CHUNK(c, CAh, CAl, NAh, NAl, PF) {                              \
  if (PF) LOADA(NAh, NAl, (c)+1);                                       \
  f32x4 acc[8];                                                         \
  _Pragma("unroll") for (int nt = 0; nt < 8; ++nt) acc[nt] = (f32x4)(0.f); \
  _Pragma("unroll") for (int kc = 0; kc < 2; ++kc){                     \
    _Pragma("unroll") for (int nt = 0; nt < 8; ++nt){                   \
      short8 bh = TB[nt*2 + kc][lane];                                  \
      short8 bl = TB[16 + nt*2 + kc][lane];                             \
      acc[nt] = __builtin_amdgcn_mfma_f32_16x16x32_bf16(CAh[kc], bh, acc[nt], 0, 0, 0); \
      acc[nt] = __builtin_amdgcn_mfma_f32_16x16x32_bf16(CAh[kc], bl, acc[nt], 0, 0, 0); \
      acc[nt] = __builtin_amdgcn_mfma_f32_16x16x32_bf16(CAl[kc], bh, acc[nt], 0, 0, 0); \
    }}                                                                  \
  _Pragma("unroll") for (int nt = 0; nt < 8; ++nt)                      \
    _Pragma("unroll") for (int r = 0; r < 4; ++r)                       \
      TT[w][g*4 + r][nt*16 + li] = acc[nt][r];                          \
  asm volatile("s_waitcnt lgkmcnt(0)" ::: "memory");                    \
  __builtin_amdgcn_sched_barrier(0);                                    \
  _Pragma("unroll") for (int k = 0; k < 4; ++k){                        \
    int rr = 4*k + g;                                                   \
    size_t rb = (size_t)((c)*64 + w*16 + rr) * NITEMS;                  \
    _Pragma("unroll") for (int h2 = 0; h2 < 2; ++h2){                   \
      int cidx = (h2*16 + li) * 4;                                      \
      int col = i0 + cidx;                                              \
      if (col < NITEMS){                                                \
        f32x4 v = *(const f32x4*)&TT[w][rr][cidx];                      \
        __builtin_nontemporal_store(v, (f32x4*)&out[rb + col]);         \
      }                                                                 \
    }}                                                                  \
  __builtin_amdgcn_sched_barrier(0); }

__global__ __launch_bounds__(256) void k_score(
    const ushort_t* __restrict__ Eh, const ushort_t* __restrict__ El,
    const float* __restrict__ T, float* __restrict__ out){
  __shared__ short8 TB[32][64];     // 32 KB: frag-ordered T tile (hi/lo)
  __shared__ float TT[4][16][132];  // 33 KB: per-wave transpose tiles
  const int t = threadIdx.x, lane = t & 63, w = t >> 6;  // 4 waves
  const int li = lane & 15, g = lane >> 4;
  const int i0 = blockIdx.x * 128;

  // ---- stage T tile (128 rows) into LDS fragment order, hi/lo bf16 ----
#pragma unroll
  for (int i = 0; i < 8; ++i){
    int e4 = t + 256 * i;            // [128 rows][16 float4-cols]
    int r = e4 >> 4, c4 = e4 & 15;
    int gi = i0 + r;
    float4 v = make_float4(0.f, 0.f, 0.f, 0.f);
    if (gi < NITEMS) v = ((const float4*)(T + (size_t)gi * 64))[c4];
    int nt = r >> 4, li2 = r & 15;
    int kc = c4 >> 3, g2 = (c4 >> 1) & 3, j0 = (c4 & 1) * 4;
    float f[4] = {v.x, v.y, v.z, v.w};
    u64_t ph = 0, pl = 0;
#pragma unroll
    for (int j = 0; j < 4; ++j){
      ushort_t hh = f2b(f[j]);
      ushort_t ll = f2b(f[j] - b2f(hh));
      ph |= (u64_t)hh << (16*j);
      pl |= (u64_t)ll << (16*j);
    }
    *(u64_t*)((ushort_t*)&TB[nt*2 + kc][g2*16 + li2] + j0) = ph;
    *(u64_t*)((ushort_t*)&TB[16 + nt*2 + kc][g2*16 + li2] + j0) = pl;
  }
  __syncthreads();

  // ---- 8 batch chunks, A double-buffered ----
  short8 Ah0[2], Al0[2], Ah1[2], Al1[2];
  LOADA(Ah0, Al0, 0);
  CHUNK(0, Ah0, Al0, Ah1, Al1, 1)
  CHUNK(1, Ah1, Al1, Ah0, Al0, 1)
  CHUNK(2, Ah0, Al0, Ah1, Al1, 1)
  CHUNK(3, Ah1, Al1, Ah0, Al0, 1)
  CHUNK(4, Ah0, Al0, Ah1, Al1, 1)
  CHUNK(5, Ah1, Al1, Ah0, Al0, 1)
  CHUNK(6, Ah0, Al0, Ah1, Al1, 1)
  CHUNK(7, Ah1, Al1, Ah0, Al0, 0)
}

// ----------------------------------------------------------------- launch --
extern "C" void kernel_launch(void* const* d_in, const int* in_sizes, int n_in,
                              void* d_out, int out_size, void* d_ws, size_t ws_size,
                              hipStream_t stream){
  const int*   ids      = (const int*)  d_in[0];
  const float* item_emb = (const float*)d_in[1];
  const float* pos_emb  = (const float*)d_in[2];
  const float* ln1g     = (const float*)d_in[3];
  const float* ln1b     = (const float*)d_in[4];
  const float* Wq       = (const float*)d_in[5];
  const float* bq       = (const float*)d_in[6];
  const float* Wk       = (const float*)d_in[7];
  const float* bk       = (const float*)d_in[8];
  const float* Wv       = (const float*)d_in[9];
  const float* bv       = (const float*)d_in[10];
  const float* ln2g     = (const float*)d_in[11];
  const float* ln2b     = (const float*)d_in[12];
  const float* W1       = (const float*)d_in[13];
  const float* b1       = (const float*)d_in[14];
  const float* W2       = (const float*)d_in[15];
  const float* b2       = (const float*)d_in[16];
  const float* lnfg     = (const float*)d_in[17];
  const float* lnfb     = (const float*)d_in[18];
  const float* items    = (const float*)d_in[19];
  float* out = (float*)d_out;

  ushort_t* Ehp = (ushort_t*)d_ws;                         // 64 KB
  ushort_t* Elp = Ehp + 512 * 64;                          // 64 KB
  short8*   Wp  = (short8*)((char*)d_ws + (256u << 10));   // 160 KB

  k_packw<<<10, 512, 0, stream>>>(Wq, Wk, Wv, W1, W2, Wp);
  // k_layers launched TWICE (idempotent) -> total - 154.9us = L(k_layers)
  k_layers<<<Bsz, 512, 0, stream>>>(ids, item_emb, pos_emb,
      ln1g, ln1b, Wp, bq, bk, bv,
      ln2g, ln2b, b1, b2, lnfg, lnfb, Ehp, Elp);
  k_layers<<<Bsz, 512, 0, stream>>>(ids, item_emb, pos_emb,
      ln1g, ln1b, Wp, bq, bk, bv,
      ln2g, ln2b, b1, b2, lnfg, lnfb, Ehp, Elp);
  k_score<<<1563, 256, 0, stream>>>(Ehp, Elp, items, out);
}

// Round 18
// 176.747 us; speedup vs baseline: 1.2022x; 1.2022x over previous
//
#include <hip/hip_runtime.h>
#include <cstddef>

// SASRec inference. Round 18: layer-2 dead-work elimination — only row 63 of
// layer-2's output feeds the final embedding, and layer-2 K/V project RAW
// seq1. Layer 2 = {K^T,V GEMM phase} + single-wave row-63 fp32 chain
// (Q/scores/softmax/PV/LN2/FFN/final-LN via readlane broadcasts), replacing
// 9 barrier phases. Layer 1 unchanged. k_packw/k_score byte-identical to R16.

#define NITEMS 200000
#define Bsz 512
#define Ssz 64
#define Dsz 64
#define EPSV 1e-3f
#define NEGV (-4294967295.0f)   // -2^32 + 1

typedef __attribute__((ext_vector_type(8))) short short8;   // 8 bf16
typedef __attribute__((ext_vector_type(4))) float f32x4;
typedef unsigned short ushort_t;
typedef unsigned long long u64_t;

static __device__ __forceinline__ float wsum(float v){
#pragma unroll
  for (int o = 32; o > 0; o >>= 1) v += __shfl_xor(v, o, 64);
  return v;
}
static __device__ __forceinline__ float wmax(float v){
#pragma unroll
  for (int o = 32; o > 0; o >>= 1) v = fmaxf(v, __shfl_xor(v, o, 64));
  return v;
}

// bf16 round-to-nearest-even (finite inputs only)
static __device__ __forceinline__ ushort_t f2b(float f){
  unsigned u = __float_as_uint(f);
  unsigned r = u + 0x7fffu + ((u >> 16) & 1u);
  return (ushort_t)(r >> 16);
}
static __device__ __forceinline__ float b2f(ushort_t h){
  return __uint_as_float(((unsigned)h) << 16);
}

// 8 consecutive f32 -> bf16 hi/lo fragments (in registers)
static __device__ __forceinline__ void a_frag(const float* __restrict__ p,
    short8& h8, short8& l8){
  float4 v0 = *(const float4*)p, v1 = *(const float4*)(p + 4);
  float f[8] = {v0.x,v0.y,v0.z,v0.w,v1.x,v1.y,v1.z,v1.w};
#pragma unroll
  for (int j = 0; j < 8; ++j){
    ushort_t hh = f2b(f[j]);
    h8[j] = (short)hh;
    l8[j] = (short)f2b(f[j] - b2f(hh));
  }
}

// ----------------------------------------------------------- weight pack ----
__global__ __launch_bounds__(512) void k_packw(const float* __restrict__ Wq,
    const float* __restrict__ Wk, const float* __restrict__ Wv,
    const float* __restrict__ W1, const float* __restrict__ W2,
    short8* __restrict__ Wp){
  const int m = blockIdx.x;            // 0..9
  const int l = m / 5, which = m % 5;
  const float* Ws[5] = {Wq, Wk, Wv, W1, W2};
  const float* Wg = Ws[which] + l * 4096;
  const int t = threadIdx.x;
  const int lane = t & 63, s = t >> 6;           // s = 0..7
  const int li = lane & 15, g = lane >> 4;
  const int cb = s >> 1, kc = s & 1;
  short8 h, lo;
#pragma unroll
  for (int j = 0; j < 8; ++j){
    float f = Wg[(kc*32 + g*8 + j)*64 + cb*16 + li];
    ushort_t hh = f2b(f);
    h[j] = (short)hh;
    lo[j] = (short)f2b(f - b2f(hh));
  }
  Wp[(m*16 + s)*64 + lane] = h;
  Wp[(m*16 + 8 + s)*64 + lane] = lo;
}

// 2-tile GEMM strip vs PACKED weight frags (8 coalesced 16B loads + MFMA)
static __device__ __forceinline__ void mmW2p(const short8 ah[2], const short8 al[2],
    const short8* __restrict__ Wp, int m, int cbh, int lane, f32x4 acc[2]){
#pragma unroll
  for (int nt = 0; nt < 2; ++nt){
    acc[nt] = (f32x4)(0.f);
#pragma unroll
    for (int kc = 0; kc < 2; ++kc){
      int s = (cbh*2 + nt)*2 + kc;
      short8 bh = Wp[(m*16 + s)*64 + lane];
      short8 bl = Wp[(m*16 + 8 + s)*64 + lane];
      acc[nt] = __builtin_amdgcn_mfma_f32_16x16x32_bf16(ah[kc], bh, acc[nt], 0, 0, 0);
      acc[nt] = __builtin_amdgcn_mfma_f32_16x16x32_bf16(ah[kc], bl, acc[nt], 0, 0, 0);
      acc[nt] = __builtin_amdgcn_mfma_f32_16x16x32_bf16(al[kc], bh, acc[nt], 0, 0, 0);
    }
  }
}

// 2-tile GEMM strip: A-frags in registers, B rows from f32 LDS ([n][k] layout)
static __device__ __forceinline__ void mmB2(const short8 ah[2], const short8 al[2],
    const float (*__restrict__ B)[68], int cbh, int li, int g, f32x4 acc[2]){
#pragma unroll
  for (int nt = 0; nt < 2; ++nt){
    acc[nt] = (f32x4)(0.f);
#pragma unroll
    for (int kc = 0; kc < 2; ++kc){
      short8 bh, bl;
      a_frag(&B[cbh*32 + nt*16 + li][kc*32 + g*8], bh, bl);
      acc[nt] = __builtin_amdgcn_mfma_f32_16x16x32_bf16(ah[kc], bh, acc[nt], 0, 0, 0);
      acc[nt] = __builtin_amdgcn_mfma_f32_16x16x32_bf16(ah[kc], bl, acc[nt], 0, 0, 0);
      acc[nt] = __builtin_amdgcn_mfma_f32_16x16x32_bf16(al[kc], bh, acc[nt], 0, 0, 0);
    }
  }
}

// ------------------------------------------------------ fused block layers --
__global__ __launch_bounds__(512, 4) void k_layers(const int* __restrict__ ids,
    const float* __restrict__ item_emb, const float* __restrict__ pos_emb,
    const float* __restrict__ ln1g, const float* __restrict__ ln1b,
    const short8* __restrict__ Wp,
    const float* __restrict__ Wqf, const float* __restrict__ W1f,
    const float* __restrict__ W2f,
    const float* __restrict__ bq, const float* __restrict__ bk,
    const float* __restrict__ bv,
    const float* __restrict__ ln2g, const float* __restrict__ ln2b,
    const float* __restrict__ b1, const float* __restrict__ b2,
    const float* __restrict__ lnfg, const float* __restrict__ lnfb,
    ushort_t* __restrict__ Eh, ushort_t* __restrict__ El){
  __shared__ float B0[64][68];   // seq -> V^T -> seq1 (layer-1 out)
  __shared__ float B1[64][68];   // xq (LN1) -> res (LN2)
  __shared__ float B2[64][68];   // Q -> scores/P -> FFN hidden -> V2 (layer 2)
  __shared__ float B3[64][68];   // K -> x -> K2^T (layer 2)

  const int t = threadIdx.x;
  const int lane = t & 63, wid = t >> 6;        // 8 waves
  const int li = lane & 15, g = lane >> 4;
  const int qb = wid & 3, cbh = wid >> 2;       // rows qb*16.., cols cbh*32..+31
  const int b = blockIdx.x;

  // ---- phase 0 (fused embed): gather + pos -> B0 (f32); ballot mask ----
#pragma unroll
  for (int it = 0; it < 2; ++it){
    int e4 = t + 512 * it;
    int r = e4 >> 4, c4 = e4 & 15, c = c4 * 4;
    int id = ids[b * Ssz + r];
    float4 v = make_float4(0.f, 0.f, 0.f, 0.f);
    if (id != NITEMS){
      float4 a = ((const float4*)(item_emb + (size_t)id * 64))[c4];
      float4 p = ((const float4*)(pos_emb + r * 64))[c4];
      v = make_float4(a.x + p.x, a.y + p.y, a.z + p.z, a.w + p.w);
    }
    *(float4*)&B0[r][c] = v;
  }
  const int myid = ids[b * Ssz + lane];
  const u64_t mvec = __ballot(myid != NITEMS);   // bit r = row r valid

  // ================= LAYER 1 (full, as R16) =================
  {
    const int l = 0, mb = 0;
    __syncthreads();

    for (int r = wid; r < 64; r += 8){
      float x = B0[r][lane];
      float mu = wsum(x) * (1.f / 64.f);
      float dv = x - mu;
      float var = wsum(dv * dv) * (1.f / 64.f);
      B1[r][lane] = dv * (1.f / sqrtf(var + EPSV)) * ln1g[l*64 + lane] + ln1b[l*64 + lane];
    }
    __syncthreads();

    short8 a0h[2], a0l[2], a1h[2], a1l[2];
#pragma unroll
    for (int kc = 0; kc < 2; ++kc){
      a_frag(&B0[qb*16 + li][kc*32 + g*8], a0h[kc], a0l[kc]);
      a_frag(&B1[qb*16 + li][kc*32 + g*8], a1h[kc], a1l[kc]);
    }
    { f32x4 acc[2]; mmW2p(a1h, a1l, Wp, mb + 0, cbh, lane, acc);
#pragma unroll
      for (int nt = 0; nt < 2; ++nt){
        int col = cbh*32 + nt*16 + li; float bb = bq[l*64 + col];
#pragma unroll
        for (int r4 = 0; r4 < 4; ++r4) B2[qb*16 + g*4 + r4][col] = acc[nt][r4] + bb;
      }
    }
    { f32x4 acc[2]; mmW2p(a0h, a0l, Wp, mb + 1, cbh, lane, acc);
#pragma unroll
      for (int nt = 0; nt < 2; ++nt){
        int col = cbh*32 + nt*16 + li; float bb = bk[l*64 + col];
#pragma unroll
        for (int r4 = 0; r4 < 4; ++r4) B3[qb*16 + g*4 + r4][col] = acc[nt][r4] + bb;
      }
    }
    __syncthreads();

    { f32x4 acc[2]; mmW2p(a0h, a0l, Wp, mb + 2, cbh, lane, acc);
#pragma unroll
      for (int nt = 0; nt < 2; ++nt){
        int col = cbh*32 + nt*16 + li; float bb = bv[l*64 + col];
#pragma unroll
        for (int r4 = 0; r4 < 4; ++r4) B0[col][qb*16 + g*4 + r4] = acc[nt][r4] + bb;
      }
    }
    short8 qh[2], ql[2];
#pragma unroll
    for (int kc = 0; kc < 2; ++kc)
      a_frag(&B2[qb*16 + li][kc*32 + g*8], qh[kc], ql[kc]);
    __syncthreads();

    { f32x4 acc[2]; mmB2(qh, ql, B3, cbh, li, g, acc);
#pragma unroll
      for (int nt = 0; nt < 2; ++nt){
        int col = cbh*32 + nt*16 + li;
#pragma unroll
        for (int r4 = 0; r4 < 4; ++r4) B2[qb*16 + g*4 + r4][col] = acc[nt][r4];
      }
    }
    __syncthreads();

    for (int r = wid; r < 64; r += 8){
      float raw = B2[r][lane];
      bool valid = (lane <= r) && ((mvec >> lane) & 1);
      float sc = valid ? raw * 0.125f : NEGV;
      float m = wmax(sc);
      float e = __expf(sc - m);
      float ssumv = wsum(e);
      float qm = ((mvec >> r) & 1) ? 1.f : 0.f;
      B2[r][lane] = (e / ssumv) * qm;
    }
    __syncthreads();

    { short8 pfh[2], pfl[2];
#pragma unroll
      for (int kc = 0; kc < 2; ++kc)
        a_frag(&B2[qb*16 + li][kc*32 + g*8], pfh[kc], pfl[kc]);
      f32x4 acc[2]; mmB2(pfh, pfl, B0, cbh, li, g, acc);
#pragma unroll
      for (int nt = 0; nt < 2; ++nt){
        int col = cbh*32 + nt*16 + li;
#pragma unroll
        for (int r4 = 0; r4 < 4; ++r4){
          int row = qb*16 + g*4 + r4;
          B3[row][col] = acc[nt][r4] + B1[row][col];
        }
      }
    }
    __syncthreads();

    for (int r = wid; r < 64; r += 8){
      float x = B3[r][lane];
      float mu = wsum(x) * (1.f / 64.f);
      float dv = x - mu;
      float var = wsum(dv * dv) * (1.f / 64.f);
      B1[r][lane] = dv * (1.f / sqrtf(var + EPSV)) * ln2g[l*64 + lane] + ln2b[l*64 + lane];
    }
    __syncthreads();

    { short8 rh[2], rl[2];
#pragma unroll
      for (int kc = 0; kc < 2; ++kc)
        a_frag(&B1[qb*16 + li][kc*32 + g*8], rh[kc], rl[kc]);
      f32x4 acc[2]; mmW2p(rh, rl, Wp, mb + 3, cbh, lane, acc);
#pragma unroll
      for (int nt = 0; nt < 2; ++nt){
        int col = cbh*32 + nt*16 + li; float bb = b1[l*64 + col];
#pragma unroll
        for (int r4 = 0; r4 < 4; ++r4)
          B2[qb*16 + g*4 + r4][col] = fmaxf(acc[nt][r4] + bb, 0.f);
      }
    }
    __syncthreads();

    { short8 hh[2], hl[2];
#pragma unroll
      for (int kc = 0; kc < 2; ++kc)
        a_frag(&B2[qb*16 + li][kc*32 + g*8], hh[kc], hl[kc]);
      f32x4 acc[2]; mmW2p(hh, hl, Wp, mb + 4, cbh, lane, acc);
#pragma unroll
      for (int nt = 0; nt < 2; ++nt){
        int col = cbh*32 + nt*16 + li; float bb = b2[l*64 + col];
#pragma unroll
        for (int r4 = 0; r4 < 4; ++r4){
          int row = qb*16 + g*4 + r4;
          float m = ((mvec >> row) & 1) ? 1.f : 0.f;
          B0[row][col] = (acc[nt][r4] + bb + B1[row][col]) * m;
        }
      }
    }
  }

  // ================= LAYER 2 (row-63 only) =================
  __syncthreads();   // B0 = seq1 complete

  // phase A: K2^T -> B3[col][row], V2 -> B2[row][col]  (from raw seq1 frags)
  {
    short8 s0h[2], s0l[2];
#pragma unroll
    for (int kc = 0; kc < 2; ++kc)
      a_frag(&B0[qb*16 + li][kc*32 + g*8], s0h[kc], s0l[kc]);
    { f32x4 acc[2]; mmW2p(s0h, s0l, Wp, 5 + 1, cbh, lane, acc);
#pragma unroll
      for (int nt = 0; nt < 2; ++nt){
        int col = cbh*32 + nt*16 + li; float bb = bk[64 + col];
#pragma unroll
        for (int r4 = 0; r4 < 4; ++r4) B3[col][qb*16 + g*4 + r4] = acc[nt][r4] + bb;
      }
    }
    { f32x4 acc[2]; mmW2p(s0h, s0l, Wp, 5 + 2, cbh, lane, acc);
#pragma unroll
      for (int nt = 0; nt < 2; ++nt){
        int col = cbh*32 + nt*16 + li; float bb = bv[64 + col];
#pragma unroll
        for (int r4 = 0; r4 < 4; ++r4) B2[qb*16 + g*4 + r4][col] = acc[nt][r4] + bb;
      }
    }
  }
  __syncthreads();

  // single-wave row-63 chain (fp32, readlane broadcasts, coalesced reads)
  if (wid == 0){
    // LN1 of seq1 row 63
    float x = B0[63][lane];
    float mu = wsum(x) * (1.f / 64.f);
    float dv = x - mu;
    float var = wsum(dv * dv) * (1.f / 64.f);
    float xq = dv * (1.f / sqrtf(var + EPSV)) * ln1g[64 + lane] + ln1b[64 + lane];

    // q = xq @ Wq2 + bq2
    float q = bq[64 + lane];
#pragma unroll
    for (int k = 0; k < 64; ++k)
      q = fmaf(__shfl(xq, k), Wqf[4096 + k*64 + lane], q);

    // scores vs K2^T, masked softmax (row 63: causal always true)
    float raw = 0.f;
#pragma unroll
    for (int k = 0; k < 64; ++k)
      raw = fmaf(__shfl(q, k), B3[k][lane], raw);
    bool kvalid = (mvec >> lane) & 1;
    float sc = kvalid ? raw * 0.125f : NEGV;
    float m = wmax(sc);
    float e = __expf(sc - m);
    float ssumv = wsum(e);
    float qm = (mvec >> 63) ? 1.f : 0.f;   // bit 63 (top bit)
    float p = (e / ssumv) * qm;

    // attn out + residual
    float o = 0.f;
#pragma unroll
    for (int j = 0; j < 64; ++j)
      o = fmaf(__shfl(p, j), B2[j][lane], o);
    float x2 = o + xq;

    // LN2
    float mu2 = wsum(x2) * (1.f / 64.f);
    float dv2 = x2 - mu2;
    float var2 = wsum(dv2 * dv2) * (1.f / 64.f);
    float res = dv2 * (1.f / sqrtf(var2 + EPSV)) * ln2g[64 + lane] + ln2b[64 + lane];

    // FFN
    float h = b1[64 + lane];
#pragma unroll
    for (int k = 0; k < 64; ++k)
      h = fmaf(__shfl(res, k), W1f[4096 + k*64 + lane], h);
    h = fmaxf(h, 0.f);
    float o2 = b2[64 + lane];
#pragma unroll
    for (int k = 0; k < 64; ++k)
      o2 = fmaf(__shfl(h, k), W2f[4096 + k*64 + lane], o2);
    o2 = (o2 + res) * qm;

    // final LN -> packed bf16 hi/lo E
    float mu3 = wsum(o2) * (1.f / 64.f);
    float dv3 = o2 - mu3;
    float var3 = wsum(dv3 * dv3) * (1.f / 64.f);
    float ef = dv3 * (1.f / sqrtf(var3 + EPSV)) * lnfg[lane] + lnfb[lane];
    ushort_t hh = f2b(ef);
    Eh[b * 64 + lane] = hh;
    El[b * 64 + lane] = f2b(ef - b2f(hh));
  }
}

// --------------------------------------------------------------- scoring ---
// R16 kernel: contiguous 256B NT stores (write-allocate elided).
#define LOADA(DH, DL, c) { int er = (c)*64 + w*16 + li;                 \
  DH[0] = *(const short8*)&Eh[er*64 + g*8];                             \
  DH[1] = *(const short8*)&Eh[er*64 + 32 + g*8];                        \
  DL[0] = *(const short8*)&El[er*64 + g*8];                             \
  DL[1] = *(const short8*)&El[er*64 + 32 + g*8]; }

#define CHUNK(c, CAh, CAl, NAh, NAl, PF) {                              \
  if (PF) LOADA(NAh, NAl, (c)+1);                                       \
  f32x4 acc[8];                                                         \
  _Pragma("unroll") for (int nt = 0; nt < 8; ++nt) acc[nt] = (f32x4)(0.f); \
  _Pragma("unroll") for (int kc = 0; kc < 2; ++kc){                     \
    _Pragma("unroll") for (int nt = 0; nt < 8; ++nt){                   \
      short8 bh = TB[nt*2 + kc][lane];                                  \
      short8 bl = TB[16 + nt*2 + kc][lane];                             \
      acc[nt] = __builtin_amdgcn_mfma_f32_16x16x32_bf16(CAh[kc], bh, acc[nt], 0, 0, 0); \
      acc[nt] = __builtin_amdgcn_mfma_f32_16x16x32_bf16(CAh[kc], bl, acc[nt], 0, 0, 0); \
      acc[nt] = __builtin_amdgcn_mfma_f32_16x16x32_bf16(CAl[kc], bh, acc[nt], 0, 0, 0); \
    }}                                                                  \
  _Pragma("unroll") for (int nt = 0; nt < 8; ++nt)                      \
    _Pragma("unroll") for (int r = 0; r < 4; ++r)                       \
      TT[w][g*4 + r][nt*16 + li] = acc[nt][r];                          \
  asm volatile("s_waitcnt lgkmcnt(0)" ::: "memory");                    \
  __builtin_amdgcn_sched_barrier(0);                                    \
  _Pragma("unroll") for (int k = 0; k < 4; ++k){                        \
    int rr = 4*k + g;                                                   \
    size_t rb = (size_t)((c)*64 + w*16 + rr) * NITEMS;                  \
    _Pragma("unroll") for (int h2 = 0; h2 < 2; ++h2){                   \
      int cidx = (h2*16 + li) * 4;                                      \
      int col = i0 + cidx;                                              \
      if (col < NITEMS){                                                \
        f32x4 v = *(const f32x4*)&TT[w][rr][cidx];                      \
        __builtin_nontemporal_store(v, (f32x4*)&out[rb + col]);         \
      }                                                                 \
    }}                                                                  \
  __builtin_amdgcn_sched_barrier(0); }

__global__ __launch_bounds__(256) void k_score(
    const ushort_t* __restrict__ Eh, const ushort_t* __restrict__ El,
    const float* __restrict__ T, float* __restrict__ out){
  __shared__ short8 TB[32][64];     // 32 KB: frag-ordered T tile (hi/lo)
  __shared__ float TT[4][16][132];  // 33 KB: per-wave transpose tiles
  const int t = threadIdx.x, lane = t & 63, w = t >> 6;  // 4 waves
  const int li = lane & 15, g = lane >> 4;
  const int i0 = blockIdx.x * 128;

  // ---- stage T tile (128 rows) into LDS fragment order, hi/lo bf16 ----
#pragma unroll
  for (int i = 0; i < 8; ++i){
    int e4 = t + 256 * i;            // [128 rows][16 float4-cols]
    int r = e4 >> 4, c4 = e4 & 15;
    int gi = i0 + r;
    float4 v = make_float4(0.f, 0.f, 0.f, 0.f);
    if (gi < NITEMS) v = ((const float4*)(T + (size_t)gi * 64))[c4];
    int nt = r >> 4, li2 = r & 15;
    int kc = c4 >> 3, g2 = (c4 >> 1) & 3, j0 = (c4 & 1) * 4;
    float f[4] = {v.x, v.y, v.z, v.w};
    u64_t ph = 0, pl = 0;
#pragma unroll
    for (int j = 0; j < 4; ++j){
      ushort_t hh = f2b(f[j]);
      ushort_t ll = f2b(f[j] - b2f(hh));
      ph |= (u64_t)hh << (16*j);
      pl |= (u64_t)ll << (16*j);
    }
    *(u64_t*)((ushort_t*)&TB[nt*2 + kc][g2*16 + li2] + j0) = ph;
    *(u64_t*)((ushort_t*)&TB[16 + nt*2 + kc][g2*16 + li2] + j0) = pl;
  }
  __syncthreads();

  // ---- 8 batch chunks, A double-buffered ----
  short8 Ah0[2], Al0[2], Ah1[2], Al1[2];
  LOADA(Ah0, Al0, 0);
  CHUNK(0, Ah0, Al0, Ah1, Al1, 1)
  CHUNK(1, Ah1, Al1, Ah0, Al0, 1)
  CHUNK(2, Ah0, Al0, Ah1, Al1, 1)
  CHUNK(3, Ah1, Al1, Ah0, Al0, 1)
  CHUNK(4, Ah0, Al0, Ah1, Al1, 1)
  CHUNK(5, Ah1, Al1, Ah0, Al0, 1)
  CHUNK(6, Ah0, Al0, Ah1, Al1, 1)
  CHUNK(7, Ah1, Al1, Ah0, Al0, 0)
}

// ----------------------------------------------------------------- launch --
extern "C" void kernel_launch(void* const* d_in, const int* in_sizes, int n_in,
                              void* d_out, int out_size, void* d_ws, size_t ws_size,
                              hipStream_t stream){
  const int*   ids      = (const int*)  d_in[0];
  const float* item_emb = (const float*)d_in[1];
  const float* pos_emb  = (const float*)d_in[2];
  const float* ln1g     = (const float*)d_in[3];
  const float* ln1b     = (const float*)d_in[4];
  const float* Wq       = (const float*)d_in[5];
  const float* bq       = (const float*)d_in[6];
  const float* Wk       = (const float*)d_in[7];
  const float* bk       = (const float*)d_in[8];
  const float* Wv       = (const float*)d_in[9];
  const float* bv       = (const float*)d_in[10];
  const float* ln2g     = (const float*)d_in[11];
  const float* ln2b     = (const float*)d_in[12];
  const float* W1       = (const float*)d_in[13];
  const float* b1       = (const float*)d_in[14];
  const float* W2       = (const float*)d_in[15];
  const float* b2       = (const float*)d_in[16];
  const float* lnfg     = (const float*)d_in[17];
  const float* lnfb     = (const float*)d_in[18];
  const float* items    = (const float*)d_in[19];
  float* out = (float*)d_out;

  ushort_t* Ehp = (ushort_t*)d_ws;                         // 64 KB
  ushort_t* Elp = Ehp + 512 * 64;                          // 64 KB
  short8*   Wp  = (short8*)((char*)d_ws + (256u << 10));   // 160 KB

  k_packw<<<10, 512, 0, stream>>>(Wq, Wk, Wv, W1, W2, Wp);
  k_layers<<<Bsz, 512, 0, stream>>>(ids, item_emb, pos_emb,
      ln1g, ln1b, Wp, Wq, W1, W2, bq, bk, bv,
      ln2g, ln2b, b1, b2, lnfg, lnfb, Ehp, Elp);
  k_score<<<1563, 256, 0, stream>>>(Ehp, Elp, items, out);
}

// Round 19
// 174.465 us; speedup vs baseline: 1.2180x; 1.0131x over previous
//
#include <hip/hip_runtime.h>
#include <cstddef>

// SASRec inference. Round 19: k_layers phase-overhead amortization test —
// TWO sequences per block (256 blocks, 8 waves; 4 waves/seq, each wave owns a
// 16x64 strip = 4 MFMA tiles), LDS 139KB (1 block/CU), launch_bounds(512,2)
// -> 256-VGPR cap. Same 18 phases, 2x work per phase. Math bit-identical.
// k_packw / k_score byte-identical to R16 (best, 154.9us).

#define NITEMS 200000
#define Bsz 512
#define Ssz 64
#define Dsz 64
#define EPSV 1e-3f
#define NEGV (-4294967295.0f)   // -2^32 + 1

typedef __attribute__((ext_vector_type(8))) short short8;   // 8 bf16
typedef __attribute__((ext_vector_type(4))) float f32x4;
typedef unsigned short ushort_t;
typedef unsigned long long u64_t;

static __device__ __forceinline__ float wsum(float v){
#pragma unroll
  for (int o = 32; o > 0; o >>= 1) v += __shfl_xor(v, o, 64);
  return v;
}
static __device__ __forceinline__ float wmax(float v){
#pragma unroll
  for (int o = 32; o > 0; o >>= 1) v = fmaxf(v, __shfl_xor(v, o, 64));
  return v;
}

// bf16 round-to-nearest-even (finite inputs only)
static __device__ __forceinline__ ushort_t f2b(float f){
  unsigned u = __float_as_uint(f);
  unsigned r = u + 0x7fffu + ((u >> 16) & 1u);
  return (ushort_t)(r >> 16);
}
static __device__ __forceinline__ float b2f(ushort_t h){
  return __uint_as_float(((unsigned)h) << 16);
}

// 8 consecutive f32 -> bf16 hi/lo fragments (in registers)
static __device__ __forceinline__ void a_frag(const float* __restrict__ p,
    short8& h8, short8& l8){
  float4 v0 = *(const float4*)p, v1 = *(const float4*)(p + 4);
  float f[8] = {v0.x,v0.y,v0.z,v0.w,v1.x,v1.y,v1.z,v1.w};
#pragma unroll
  for (int j = 0; j < 8; ++j){
    ushort_t hh = f2b(f[j]);
    h8[j] = (short)hh;
    l8[j] = (short)f2b(f[j] - b2f(hh));
  }
}

// ----------------------------------------------------------- weight pack ----
__global__ __launch_bounds__(512) void k_packw(const float* __restrict__ Wq,
    const float* __restrict__ Wk, const float* __restrict__ Wv,
    const float* __restrict__ W1, const float* __restrict__ W2,
    short8* __restrict__ Wp){
  const int m = blockIdx.x;            // 0..9
  const int l = m / 5, which = m % 5;
  const float* Ws[5] = {Wq, Wk, Wv, W1, W2};
  const float* Wg = Ws[which] + l * 4096;
  const int t = threadIdx.x;
  const int lane = t & 63, s = t >> 6;           // s = 0..7
  const int li = lane & 15, g = lane >> 4;
  const int cb = s >> 1, kc = s & 1;
  short8 h, lo;
#pragma unroll
  for (int j = 0; j < 8; ++j){
    float f = Wg[(kc*32 + g*8 + j)*64 + cb*16 + li];
    ushort_t hh = f2b(f);
    h[j] = (short)hh;
    lo[j] = (short)f2b(f - b2f(hh));
  }
  Wp[(m*16 + s)*64 + lane] = h;
  Wp[(m*16 + 8 + s)*64 + lane] = lo;
}

// 4-tile (16x64) GEMM strip vs PACKED weight frags
static __device__ __forceinline__ void mmW4p(const short8 ah[2], const short8 al[2],
    const short8* __restrict__ Wp, int m, int lane, f32x4 acc[4]){
#pragma unroll
  for (int nt = 0; nt < 4; ++nt){
    acc[nt] = (f32x4)(0.f);
#pragma unroll
    for (int kc = 0; kc < 2; ++kc){
      int s = nt*2 + kc;
      short8 bh = Wp[(m*16 + s)*64 + lane];
      short8 bl = Wp[(m*16 + 8 + s)*64 + lane];
      acc[nt] = __builtin_amdgcn_mfma_f32_16x16x32_bf16(ah[kc], bh, acc[nt], 0, 0, 0);
      acc[nt] = __builtin_amdgcn_mfma_f32_16x16x32_bf16(ah[kc], bl, acc[nt], 0, 0, 0);
      acc[nt] = __builtin_amdgcn_mfma_f32_16x16x32_bf16(al[kc], bh, acc[nt], 0, 0, 0);
    }
  }
}

// 4-tile GEMM strip: A-frags in registers, B rows from f32 LDS ([n][k])
static __device__ __forceinline__ void mmB4(const short8 ah[2], const short8 al[2],
    const float (*__restrict__ B)[68], int li, int g, f32x4 acc[4]){
#pragma unroll
  for (int nt = 0; nt < 4; ++nt){
    acc[nt] = (f32x4)(0.f);
#pragma unroll
    for (int kc = 0; kc < 2; ++kc){
      short8 bh, bl;
      a_frag(&B[nt*16 + li][kc*32 + g*8], bh, bl);
      acc[nt] = __builtin_amdgcn_mfma_f32_16x16x32_bf16(ah[kc], bh, acc[nt], 0, 0, 0);
      acc[nt] = __builtin_amdgcn_mfma_f32_16x16x32_bf16(ah[kc], bl, acc[nt], 0, 0, 0);
      acc[nt] = __builtin_amdgcn_mfma_f32_16x16x32_bf16(al[kc], bh, acc[nt], 0, 0, 0);
    }
  }
}

// ------------------------------------------------------ fused block layers --
// 2 sequences per block: waves 0-3 -> seq b*2, waves 4-7 -> seq b*2+1.
__global__ __launch_bounds__(512, 2) void k_layers(const int* __restrict__ ids,
    const float* __restrict__ item_emb, const float* __restrict__ pos_emb,
    const float* __restrict__ ln1g, const float* __restrict__ ln1b,
    const short8* __restrict__ Wp,
    const float* __restrict__ bq, const float* __restrict__ bk,
    const float* __restrict__ bv,
    const float* __restrict__ ln2g, const float* __restrict__ ln2b,
    const float* __restrict__ b1, const float* __restrict__ b2,
    const float* __restrict__ lnfg, const float* __restrict__ lnfb,
    ushort_t* __restrict__ Eh, ushort_t* __restrict__ El){
  __shared__ float B0[2][64][68];   // seq -> V^T -> (next) seq
  __shared__ float B1[2][64][68];   // xq (LN1) -> res (LN2)
  __shared__ float B2[2][64][68];   // Q -> scores/P -> FFN hidden
  __shared__ float B3[2][64][68];   // K -> x (attn+residual)

  const int t = threadIdx.x;
  const int lane = t & 63, wid = t >> 6;        // 8 waves
  const int li = lane & 15, g = lane >> 4;
  const int sq = wid >> 2, qb = wid & 3;        // seq half + row-block
  const int b = blockIdx.x;

  // ---- phase 0 (fused embed): gather + pos -> B0; ballot masks ----
#pragma unroll
  for (int it = 0; it < 4; ++it){
    int e4 = t + 512 * it;                  // 0..2047 over [2][64][16]
    int s2 = e4 >> 10, r = (e4 >> 4) & 63, c4 = e4 & 15, c = c4 * 4;
    int id = ids[(b*2 + s2) * Ssz + r];
    float4 v = make_float4(0.f, 0.f, 0.f, 0.f);
    if (id != NITEMS){
      float4 a = ((const float4*)(item_emb + (size_t)id * 64))[c4];
      float4 p = ((const float4*)(pos_emb + r * 64))[c4];
      v = make_float4(a.x + p.x, a.y + p.y, a.z + p.z, a.w + p.w);
    }
    *(float4*)&B0[s2][r][c] = v;
  }
  const int myid = ids[(b*2 + sq) * Ssz + lane];
  const u64_t mvec = __ballot(myid != NITEMS);   // per-wave = per-seq mask

  for (int l = 0; l < 2; ++l){
    const int mb = l * 5;
    __syncthreads();   // fences phase-0 (l=0) / previous layer-out (l=1)

    // ---- LN1: B0 -> B1 (16 rows per wave, 4 waves/seq) ----
    for (int r = qb; r < 64; r += 4){
      float x = B0[sq][r][lane];
      float mu = wsum(x) * (1.f / 64.f);
      float dv = x - mu;
      float var = wsum(dv * dv) * (1.f / 64.f);
      B1[sq][r][lane] = dv * (1.f / sqrtf(var + EPSV)) * ln1g[l*64 + lane] + ln1b[l*64 + lane];
    }
    __syncthreads();

    // ---- ph1: A-frags of seq (B0) and LN1 (B1); Q -> B2, K -> B3 ----
    short8 a0h[2], a0l[2], a1h[2], a1l[2];
#pragma unroll
    for (int kc = 0; kc < 2; ++kc){
      a_frag(&B0[sq][qb*16 + li][kc*32 + g*8], a0h[kc], a0l[kc]);
      a_frag(&B1[sq][qb*16 + li][kc*32 + g*8], a1h[kc], a1l[kc]);
    }
    { f32x4 acc[4]; mmW4p(a1h, a1l, Wp, mb + 0, lane, acc);
#pragma unroll
      for (int nt = 0; nt < 4; ++nt){
        int col = nt*16 + li; float bb = bq[l*64 + col];
#pragma unroll
        for (int r4 = 0; r4 < 4; ++r4) B2[sq][qb*16 + g*4 + r4][col] = acc[nt][r4] + bb;
      }
    }
    { f32x4 acc[4]; mmW4p(a0h, a0l, Wp, mb + 1, lane, acc);
#pragma unroll
      for (int nt = 0; nt < 4; ++nt){
        int col = nt*16 + li; float bb = bk[l*64 + col];
#pragma unroll
        for (int r4 = 0; r4 < 4; ++r4) B3[sq][qb*16 + g*4 + r4][col] = acc[nt][r4] + bb;
      }
    }
    __syncthreads();

    // ---- ph2: V (from seq frags) -> B0 transposed; snapshot Q frags ----
    { f32x4 acc[4]; mmW4p(a0h, a0l, Wp, mb + 2, lane, acc);
#pragma unroll
      for (int nt = 0; nt < 4; ++nt){
        int col = nt*16 + li; float bb = bv[l*64 + col];
#pragma unroll
        for (int r4 = 0; r4 < 4; ++r4) B0[sq][col][qb*16 + g*4 + r4] = acc[nt][r4] + bb;
      }
    }
    short8 qh[2], ql[2];
#pragma unroll
    for (int kc = 0; kc < 2; ++kc)
      a_frag(&B2[sq][qb*16 + li][kc*32 + g*8], qh[kc], ql[kc]);
    __syncthreads();

    // ---- ph3: scores = Q @ K^T -> B2 (Q dead, snapshotted) ----
    { f32x4 acc[4]; mmB4(qh, ql, B3[sq], li, g, acc);
#pragma unroll
      for (int nt = 0; nt < 4; ++nt){
        int col = nt*16 + li;
#pragma unroll
        for (int r4 = 0; r4 < 4; ++r4) B2[sq][qb*16 + g*4 + r4][col] = acc[nt][r4];
      }
    }
    __syncthreads();

    // ---- ph4: masked softmax in place (B2) ----
    for (int r = qb; r < 64; r += 4){
      float raw = B2[sq][r][lane];
      bool valid = (lane <= r) && ((mvec >> lane) & 1);
      float sc = valid ? raw * 0.125f : NEGV;
      float m = wmax(sc);
      float e = __expf(sc - m);
      float ssumv = wsum(e);
      float qm = ((mvec >> r) & 1) ? 1.f : 0.f;
      B2[sq][r][lane] = (e / ssumv) * qm;
    }
    __syncthreads();

    // ---- ph5: x = P @ V + xq -> B3 (K dead) ----
    { short8 pfh[2], pfl[2];
#pragma unroll
      for (int kc = 0; kc < 2; ++kc)
        a_frag(&B2[sq][qb*16 + li][kc*32 + g*8], pfh[kc], pfl[kc]);
      f32x4 acc[4]; mmB4(pfh, pfl, B0[sq], li, g, acc);
#pragma unroll
      for (int nt = 0; nt < 4; ++nt){
        int col = nt*16 + li;
#pragma unroll
        for (int r4 = 0; r4 < 4; ++r4){
          int row = qb*16 + g*4 + r4;
          B3[sq][row][col] = acc[nt][r4] + B1[sq][row][col];
        }
      }
    }
    __syncthreads();

    // ---- ph6: LN2: B3 -> B1 (xq dead) ----
    for (int r = qb; r < 64; r += 4){
      float x = B3[sq][r][lane];
      float mu = wsum(x) * (1.f / 64.f);
      float dv = x - mu;
      float var = wsum(dv * dv) * (1.f / 64.f);
      B1[sq][r][lane] = dv * (1.f / sqrtf(var + EPSV)) * ln2g[l*64 + lane] + ln2b[l*64 + lane];
    }
    __syncthreads();

    // ---- ph7: h = relu(res @ W1 + b1) -> B2 (P dead) ----
    { short8 rh[2], rl[2];
#pragma unroll
      for (int kc = 0; kc < 2; ++kc)
        a_frag(&B1[sq][qb*16 + li][kc*32 + g*8], rh[kc], rl[kc]);
      f32x4 acc[4]; mmW4p(rh, rl, Wp, mb + 3, lane, acc);
#pragma unroll
      for (int nt = 0; nt < 4; ++nt){
        int col = nt*16 + li; float bb = b1[l*64 + col];
#pragma unroll
        for (int r4 = 0; r4 < 4; ++r4)
          B2[sq][qb*16 + g*4 + r4][col] = fmaxf(acc[nt][r4] + bb, 0.f);
      }
    }
    __syncthreads();

    // ---- ph8: out = (h @ W2 + b2 + res) * mask -> B0 (V^T dead) ----
    { short8 hh[2], hl[2];
#pragma unroll
      for (int kc = 0; kc < 2; ++kc)
        a_frag(&B2[sq][qb*16 + li][kc*32 + g*8], hh[kc], hl[kc]);
      f32x4 acc[4]; mmW4p(hh, hl, Wp, mb + 4, lane, acc);
#pragma unroll
      for (int nt = 0; nt < 4; ++nt){
        int col = nt*16 + li; float bb = b2[l*64 + col];
#pragma unroll
        for (int r4 = 0; r4 < 4; ++r4){
          int row = qb*16 + g*4 + r4;
          float m = ((mvec >> row) & 1) ? 1.f : 0.f;
          B0[sq][row][col] = (acc[nt][r4] + bb + B1[sq][row][col]) * m;
        }
      }
    }
  }

  // ---- fused final LN on row 63 -> packed bf16 hi/lo E (one wave/seq) ----
  __syncthreads();
  if (qb == 0){
    float x = B0[sq][63][lane];
    float mu = wsum(x) * (1.f / 64.f);
    float dv = x - mu;
    float var = wsum(dv * dv) * (1.f / 64.f);
    float o = dv * (1.f / sqrtf(var + EPSV)) * lnfg[lane] + lnfb[lane];
    ushort_t h = f2b(o);
    Eh[(b*2 + sq) * 64 + lane] = h;
    El[(b*2 + sq) * 64 + lane] = f2b(o - b2f(h));
  }
}

// --------------------------------------------------------------- scoring ---
// R16 kernel: contiguous 256B NT stores (write-allocate elided).
#define LOADA(DH, DL, c) { int er = (c)*64 + w*16 + li;                 \
  DH[0] = *(const short8*)&Eh[er*64 + g*8];                             \
  DH[1] = *(const short8*)&Eh[er*64 + 32 + g*8];                        \
  DL[0] = *(const short8*)&El[er*64 + g*8];                             \
  DL[1] = *(const short8*)&El[er*64 + 32 + g*8]; }

#define CHUNK(c, CAh, CAl, NAh, NAl, PF) {                              \
  if (PF) LOADA(NAh, NAl, (c)+1);                                       \
  f32x4 acc[8];                                                         \
  _Pragma("unroll") for (int nt = 0; nt < 8; ++nt) acc[nt] = (f32x4)(0.f); \
  _Pragma("unroll") for (int kc = 0; kc < 2; ++kc){                     \
    _Pragma("unroll") for (int nt = 0; nt < 8; ++nt){                   \
      short8 bh = TB[nt*2 + kc][lane];                                  \
      short8 bl = TB[16 + nt*2 + kc][lane];                             \
      acc[nt] = __builtin_amdgcn_mfma_f32_16x16x32_bf16(CAh[kc], bh, acc[nt], 0, 0, 0); \
      acc[nt] = __builtin_amdgcn_mfma_f32_16x16x32_bf16(CAh[kc], bl, acc[nt], 0, 0, 0); \
      acc[nt] = __builtin_amdgcn_mfma_f32_16x16x32_bf16(CAl[kc], bh, acc[nt], 0, 0, 0); \
    }}                                                                  \
  _Pragma("unroll") for (int nt = 0; nt < 8; ++nt)                      \
    _Pragma("unroll") for (int r = 0; r < 4; ++r)                       \
      TT[w][g*4 + r][nt*16 + li] = acc[nt][r];                          \
  asm volatile("s_waitcnt lgkmcnt(0)" ::: "memory");                    \
  __builtin_amdgcn_sched_barrier(0);                                    \
  _Pragma("unroll") for (int k = 0; k < 4; ++k){                        \
    int rr = 4*k + g;                                                   \
    size_t rb = (size_t)((c)*64 + w*16 + rr) * NITEMS;                  \
    _Pragma("unroll") for (int h2 = 0; h2 < 2; ++h2){                   \
      int cidx = (h2*16 + li) * 4;                                      \
      int col = i0 + cidx;                                              \
      if (col < NITEMS){                                                \
        f32x4 v = *(const f32x4*)&TT[w][rr][cidx];                      \
        __builtin_nontemporal_store(v, (f32x4*)&out[rb + col]);         \
      }                                                                 \
    }}                                                                  \
  __builtin_amdgcn_sched_barrier(0); }

__global__ __launch_bounds__(256) void k_score(
    const ushort_t* __restrict__ Eh, const ushort_t* __restrict__ El,
    const float* __restrict__ T, float* __restrict__ out){
  __shared__ short8 TB[32][64];     // 32 KB: frag-ordered T tile (hi/lo)
  __shared__ float TT[4][16][132];  // 33 KB: per-wave transpose tiles
  const int t = threadIdx.x, lane = t & 63, w = t >> 6;  // 4 waves
  const int li = lane & 15, g = lane >> 4;
  const int i0 = blockIdx.x * 128;

  // ---- stage T tile (128 rows) into LDS fragment order, hi/lo bf16 ----
#pragma unroll
  for (int i = 0; i < 8; ++i){
    int e4 = t + 256 * i;            // [128 rows][16 float4-cols]
    int r = e4 >> 4, c4 = e4 & 15;
    int gi = i0 + r;
    float4 v = make_float4(0.f, 0.f, 0.f, 0.f);
    if (gi < NITEMS) v = ((const float4*)(T + (size_t)gi * 64))[c4];
    int nt = r >> 4, li2 = r & 15;
    int kc = c4 >> 3, g2 = (c4 >> 1) & 3, j0 = (c4 & 1) * 4;
    float f[4] = {v.x, v.y, v.z, v.w};
    u64_t ph = 0, pl = 0;
#pragma unroll
    for (int j = 0; j < 4; ++j){
      ushort_t hh = f2b(f[j]);
      ushort_t ll = f2b(f[j] - b2f(hh));
      ph |= (u64_t)hh << (16*j);
      pl |= (u64_t)ll << (16*j);
    }
    *(u64_t*)((ushort_t*)&TB[nt*2 + kc][g2*16 + li2] + j0) = ph;
    *(u64_t*)((ushort_t*)&TB[16 + nt*2 + kc][g2*16 + li2] + j0) = pl;
  }
  __syncthreads();

  // ---- 8 batch chunks, A double-buffered ----
  short8 Ah0[2], Al0[2], Ah1[2], Al1[2];
  LOADA(Ah0, Al0, 0);
  CHUNK(0, Ah0, Al0, Ah1, Al1, 1)
  CHUNK(1, Ah1, Al1, Ah0, Al0, 1)
  CHUNK(2, Ah0, Al0, Ah1, Al1, 1)
  CHUNK(3, Ah1, Al1, Ah0, Al0, 1)
  CHUNK(4, Ah0, Al0, Ah1, Al1, 1)
  CHUNK(5, Ah1, Al1, Ah0, Al0, 1)
  CHUNK(6, Ah0, Al0, Ah1, Al1, 1)
  CHUNK(7, Ah1, Al1, Ah0, Al0, 0)
}

// ----------------------------------------------------------------- launch --
extern "C" void kernel_launch(void* const* d_in, const int* in_sizes, int n_in,
                              void* d_out, int out_size, void* d_ws, size_t ws_size,
                              hipStream_t stream){
  const int*   ids      = (const int*)  d_in[0];
  const float* item_emb = (const float*)d_in[1];
  const float* pos_emb  = (const float*)d_in[2];
  const float* ln1g     = (const float*)d_in[3];
  const float* ln1b     = (const float*)d_in[4];
  const float* Wq       = (const float*)d_in[5];
  const float* bq       = (const float*)d_in[6];
  const float* Wk       = (const float*)d_in[7];
  const float* bk       = (const float*)d_in[8];
  const float* Wv       = (const float*)d_in[9];
  const float* bv       = (const float*)d_in[10];
  const float* ln2g     = (const float*)d_in[11];
  const float* ln2b     = (const float*)d_in[12];
  const float* W1       = (const float*)d_in[13];
  const float* b1       = (const float*)d_in[14];
  const float* W2       = (const float*)d_in[15];
  const float* b2       = (const float*)d_in[16];
  const float* lnfg     = (const float*)d_in[17];
  const float* lnfb     = (const float*)d_in[18];
  const float* items    = (const float*)d_in[19];
  float* out = (float*)d_out;

  ushort_t* Ehp = (ushort_t*)d_ws;                         // 64 KB
  ushort_t* Elp = Ehp + 512 * 64;                          // 64 KB
  short8*   Wp  = (short8*)((char*)d_ws + (256u << 10));   // 160 KB

  k_packw<<<10, 512, 0, stream>>>(Wq, Wk, Wv, W1, W2, Wp);
  k_layers<<<256, 512, 0, stream>>>(ids, item_emb, pos_emb,
      ln1g, ln1b, Wp, bq, bk, bv,
      ln2g, ln2b, b1, b2, lnfg, lnfb, Ehp, Elp);
  k_score<<<1563, 256, 0, stream>>>(Ehp, Elp, items, out);
}

// Round 20
// 156.578 us; speedup vs baseline: 1.3571x; 1.1142x over previous
//
#include <hip/hip_runtime.h>
#include <cstddef>

// SASRec inference. Round 20: REVERT to R16 exactly (best: 154.9us).
// R18 (row-63 layer 2) and R19 (2-seq/block) both regressed; R16 is the
// empirical minimum. k_score: NT + 256B-contiguous stores (write-allocate
// elided, 1.15x write floor). k_layers: 512thr/2blk-per-CU + packed weights.

#define NITEMS 200000
#define Bsz 512
#define Ssz 64
#define Dsz 64
#define EPSV 1e-3f
#define NEGV (-4294967295.0f)   // -2^32 + 1

typedef __attribute__((ext_vector_type(8))) short short8;   // 8 bf16
typedef __attribute__((ext_vector_type(4))) float f32x4;
typedef unsigned short ushort_t;
typedef unsigned long long u64_t;

static __device__ __forceinline__ float wsum(float v){
#pragma unroll
  for (int o = 32; o > 0; o >>= 1) v += __shfl_xor(v, o, 64);
  return v;
}
static __device__ __forceinline__ float wmax(float v){
#pragma unroll
  for (int o = 32; o > 0; o >>= 1) v = fmaxf(v, __shfl_xor(v, o, 64));
  return v;
}

// bf16 round-to-nearest-even (finite inputs only)
static __device__ __forceinline__ ushort_t f2b(float f){
  unsigned u = __float_as_uint(f);
  unsigned r = u + 0x7fffu + ((u >> 16) & 1u);
  return (ushort_t)(r >> 16);
}
static __device__ __forceinline__ float b2f(ushort_t h){
  return __uint_as_float(((unsigned)h) << 16);
}

// 8 consecutive f32 -> bf16 hi/lo fragments (in registers)
static __device__ __forceinline__ void a_frag(const float* __restrict__ p,
    short8& h8, short8& l8){
  float4 v0 = *(const float4*)p, v1 = *(const float4*)(p + 4);
  float f[8] = {v0.x,v0.y,v0.z,v0.w,v1.x,v1.y,v1.z,v1.w};
#pragma unroll
  for (int j = 0; j < 8; ++j){
    ushort_t hh = f2b(f[j]);
    h8[j] = (short)hh;
    l8[j] = (short)f2b(f[j] - b2f(hh));
  }
}

// ----------------------------------------------------------- weight pack ----
__global__ __launch_bounds__(512) void k_packw(const float* __restrict__ Wq,
    const float* __restrict__ Wk, const float* __restrict__ Wv,
    const float* __restrict__ W1, const float* __restrict__ W2,
    short8* __restrict__ Wp){
  const int m = blockIdx.x;            // 0..9
  const int l = m / 5, which = m % 5;
  const float* Ws[5] = {Wq, Wk, Wv, W1, W2};
  const float* Wg = Ws[which] + l * 4096;
  const int t = threadIdx.x;
  const int lane = t & 63, s = t >> 6;           // s = 0..7
  const int li = lane & 15, g = lane >> 4;
  const int cb = s >> 1, kc = s & 1;
  short8 h, lo;
#pragma unroll
  for (int j = 0; j < 8; ++j){
    float f = Wg[(kc*32 + g*8 + j)*64 + cb*16 + li];
    ushort_t hh = f2b(f);
    h[j] = (short)hh;
    lo[j] = (short)f2b(f - b2f(hh));
  }
  Wp[(m*16 + s)*64 + lane] = h;
  Wp[(m*16 + 8 + s)*64 + lane] = lo;
}

// 2-tile GEMM strip vs PACKED weight frags (8 coalesced 16B loads + MFMA)
static __device__ __forceinline__ void mmW2p(const short8 ah[2], const short8 al[2],
    const short8* __restrict__ Wp, int m, int cbh, int lane, f32x4 acc[2]){
#pragma unroll
  for (int nt = 0; nt < 2; ++nt){
    acc[nt] = (f32x4)(0.f);
#pragma unroll
    for (int kc = 0; kc < 2; ++kc){
      int s = (cbh*2 + nt)*2 + kc;
      short8 bh = Wp[(m*16 + s)*64 + lane];
      short8 bl = Wp[(m*16 + 8 + s)*64 + lane];
      acc[nt] = __builtin_amdgcn_mfma_f32_16x16x32_bf16(ah[kc], bh, acc[nt], 0, 0, 0);
      acc[nt] = __builtin_amdgcn_mfma_f32_16x16x32_bf16(ah[kc], bl, acc[nt], 0, 0, 0);
      acc[nt] = __builtin_amdgcn_mfma_f32_16x16x32_bf16(al[kc], bh, acc[nt], 0, 0, 0);
    }
  }
}

// 2-tile GEMM strip: A-frags in registers, B rows from f32 LDS ([n][k] layout)
static __device__ __forceinline__ void mmB2(const short8 ah[2], const short8 al[2],
    const float (*__restrict__ B)[68], int cbh, int li, int g, f32x4 acc[2]){
#pragma unroll
  for (int nt = 0; nt < 2; ++nt){
    acc[nt] = (f32x4)(0.f);
#pragma unroll
    for (int kc = 0; kc < 2; ++kc){
      short8 bh, bl;
      a_frag(&B[cbh*32 + nt*16 + li][kc*32 + g*8], bh, bl);
      acc[nt] = __builtin_amdgcn_mfma_f32_16x16x32_bf16(ah[kc], bh, acc[nt], 0, 0, 0);
      acc[nt] = __builtin_amdgcn_mfma_f32_16x16x32_bf16(ah[kc], bl, acc[nt], 0, 0, 0);
      acc[nt] = __builtin_amdgcn_mfma_f32_16x16x32_bf16(al[kc], bh, acc[nt], 0, 0, 0);
    }
  }
}

// ------------------------------------------------------ fused block layers --
__global__ __launch_bounds__(512, 4) void k_layers(const int* __restrict__ ids,
    const float* __restrict__ item_emb, const float* __restrict__ pos_emb,
    const float* __restrict__ ln1g, const float* __restrict__ ln1b,
    const short8* __restrict__ Wp,
    const float* __restrict__ bq, const float* __restrict__ bk,
    const float* __restrict__ bv,
    const float* __restrict__ ln2g, const float* __restrict__ ln2b,
    const float* __restrict__ b1, const float* __restrict__ b2,
    const float* __restrict__ lnfg, const float* __restrict__ lnfb,
    ushort_t* __restrict__ Eh, ushort_t* __restrict__ El){
  __shared__ float B0[64][68];   // seq -> V^T -> (next) seq
  __shared__ float B1[64][68];   // xq (LN1 out) -> res (LN2 out)
  __shared__ float B2[64][68];   // Q -> scores/P -> FFN hidden
  __shared__ float B3[64][68];   // K -> x (attn+residual)

  const int t = threadIdx.x;
  const int lane = t & 63, wid = t >> 6;        // 8 waves
  const int li = lane & 15, g = lane >> 4;
  const int qb = wid & 3, cbh = wid >> 2;       // rows qb*16.., cols cbh*32..+31
  const int b = blockIdx.x;

  // ---- phase 0 (fused embed): gather + pos -> B0 (f32); ballot mask ----
#pragma unroll
  for (int it = 0; it < 2; ++it){
    int e4 = t + 512 * it;
    int r = e4 >> 4, c4 = e4 & 15, c = c4 * 4;
    int id = ids[b * Ssz + r];
    float4 v = make_float4(0.f, 0.f, 0.f, 0.f);
    if (id != NITEMS){
      float4 a = ((const float4*)(item_emb + (size_t)id * 64))[c4];
      float4 p = ((const float4*)(pos_emb + r * 64))[c4];
      v = make_float4(a.x + p.x, a.y + p.y, a.z + p.z, a.w + p.w);
    }
    *(float4*)&B0[r][c] = v;
  }
  const int myid = ids[b * Ssz + lane];
  const u64_t mvec = __ballot(myid != NITEMS);   // bit r = row r valid

  for (int l = 0; l < 2; ++l){
    const int mb = l * 5;
    __syncthreads();   // fences phase-0 (l=0) / previous layer-out (l=1)

    // ---- LN1: B0 -> B1 (8 rows/wave) ----
    for (int r = wid; r < 64; r += 8){
      float x = B0[r][lane];
      float mu = wsum(x) * (1.f / 64.f);
      float dv = x - mu;
      float var = wsum(dv * dv) * (1.f / 64.f);
      B1[r][lane] = dv * (1.f / sqrtf(var + EPSV)) * ln1g[l*64 + lane] + ln1b[l*64 + lane];
    }
    __syncthreads();

    // ---- ph1: A-frags of seq (B0) and LN1 (B1); Q -> B2, K -> B3 ----
    short8 a0h[2], a0l[2], a1h[2], a1l[2];
#pragma unroll
    for (int kc = 0; kc < 2; ++kc){
      a_frag(&B0[qb*16 + li][kc*32 + g*8], a0h[kc], a0l[kc]);
      a_frag(&B1[qb*16 + li][kc*32 + g*8], a1h[kc], a1l[kc]);
    }
    { f32x4 acc[2]; mmW2p(a1h, a1l, Wp, mb + 0, cbh, lane, acc);
#pragma unroll
      for (int nt = 0; nt < 2; ++nt){
        int col = cbh*32 + nt*16 + li; float bb = bq[l*64 + col];
#pragma unroll
        for (int r4 = 0; r4 < 4; ++r4) B2[qb*16 + g*4 + r4][col] = acc[nt][r4] + bb;
      }
    }
    { f32x4 acc[2]; mmW2p(a0h, a0l, Wp, mb + 1, cbh, lane, acc);
#pragma unroll
      for (int nt = 0; nt < 2; ++nt){
        int col = cbh*32 + nt*16 + li; float bb = bk[l*64 + col];
#pragma unroll
        for (int r4 = 0; r4 < 4; ++r4) B3[qb*16 + g*4 + r4][col] = acc[nt][r4] + bb;
      }
    }
    __syncthreads();

    // ---- ph2: V (from seq frags) -> B0 transposed; snapshot Q frags ----
    { f32x4 acc[2]; mmW2p(a0h, a0l, Wp, mb + 2, cbh, lane, acc);
#pragma unroll
      for (int nt = 0; nt < 2; ++nt){
        int col = cbh*32 + nt*16 + li; float bb = bv[l*64 + col];
#pragma unroll
        for (int r4 = 0; r4 < 4; ++r4) B0[col][qb*16 + g*4 + r4] = acc[nt][r4] + bb;
      }
    }
    short8 qh[2], ql[2];
#pragma unroll
    for (int kc = 0; kc < 2; ++kc)
      a_frag(&B2[qb*16 + li][kc*32 + g*8], qh[kc], ql[kc]);
    __syncthreads();

    // ---- ph3: scores = Q @ K^T -> B2 (Q dead, snapshotted) ----
    { f32x4 acc[2]; mmB2(qh, ql, B3, cbh, li, g, acc);
#pragma unroll
      for (int nt = 0; nt < 2; ++nt){
        int col = cbh*32 + nt*16 + li;
#pragma unroll
        for (int r4 = 0; r4 < 4; ++r4) B2[qb*16 + g*4 + r4][col] = acc[nt][r4];
      }
    }
    __syncthreads();

    // ---- ph4: masked softmax in place (B2) ----
    for (int r = wid; r < 64; r += 8){
      float raw = B2[r][lane];
      bool valid = (lane <= r) && ((mvec >> lane) & 1);
      float sc = valid ? raw * 0.125f : NEGV;
      float m = wmax(sc);
      float e = __expf(sc - m);
      float ssumv = wsum(e);
      float qm = ((mvec >> r) & 1) ? 1.f : 0.f;
      B2[r][lane] = (e / ssumv) * qm;
    }
    __syncthreads();

    // ---- ph5: x = P @ V + xq -> B3 (K dead) ----
    { short8 pfh[2], pfl[2];
#pragma unroll
      for (int kc = 0; kc < 2; ++kc)
        a_frag(&B2[qb*16 + li][kc*32 + g*8], pfh[kc], pfl[kc]);
      f32x4 acc[2]; mmB2(pfh, pfl, B0, cbh, li, g, acc);
#pragma unroll
      for (int nt = 0; nt < 2; ++nt){
        int col = cbh*32 + nt*16 + li;
#pragma unroll
        for (int r4 = 0; r4 < 4; ++r4){
          int row = qb*16 + g*4 + r4;
          B3[row][col] = acc[nt][r4] + B1[row][col];
        }
      }
    }
    __syncthreads();

    // ---- ph6: LN2: B3 -> B1 (xq dead) ----
    for (int r = wid; r < 64; r += 8){
      float x = B3[r][lane];
      float mu = wsum(x) * (1.f / 64.f);
      float dv = x - mu;
      float var = wsum(dv * dv) * (1.f / 64.f);
      B1[r][lane] = dv * (1.f / sqrtf(var + EPSV)) * ln2g[l*64 + lane] + ln2b[l*64 + lane];
    }
    __syncthreads();

    // ---- ph7: h = relu(res @ W1 + b1) -> B2 (P dead) ----
    { short8 rh[2], rl[2];
#pragma unroll
      for (int kc = 0; kc < 2; ++kc)
        a_frag(&B1[qb*16 + li][kc*32 + g*8], rh[kc], rl[kc]);
      f32x4 acc[2]; mmW2p(rh, rl, Wp, mb + 3, cbh, lane, acc);
#pragma unroll
      for (int nt = 0; nt < 2; ++nt){
        int col = cbh*32 + nt*16 + li; float bb = b1[l*64 + col];
#pragma unroll
        for (int r4 = 0; r4 < 4; ++r4)
          B2[qb*16 + g*4 + r4][col] = fmaxf(acc[nt][r4] + bb, 0.f);
      }
    }
    __syncthreads();

    // ---- ph8: out = (h @ W2 + b2 + res) * mask -> B0 (V^T dead) ----
    { short8 hh[2], hl[2];
#pragma unroll
      for (int kc = 0; kc < 2; ++kc)
        a_frag(&B2[qb*16 + li][kc*32 + g*8], hh[kc], hl[kc]);
      f32x4 acc[2]; mmW2p(hh, hl, Wp, mb + 4, cbh, lane, acc);
#pragma unroll
      for (int nt = 0; nt < 2; ++nt){
        int col = cbh*32 + nt*16 + li; float bb = b2[l*64 + col];
#pragma unroll
        for (int r4 = 0; r4 < 4; ++r4){
          int row = qb*16 + g*4 + r4;
          float m = ((mvec >> row) & 1) ? 1.f : 0.f;
          B0[row][col] = (acc[nt][r4] + bb + B1[row][col]) * m;
        }
      }
    }
  }

  // ---- fused final LN on row 63 -> packed bf16 hi/lo E ----
  __syncthreads();
  if (wid == 0){
    float x = B0[63][lane];
    float mu = wsum(x) * (1.f / 64.f);
    float dv = x - mu;
    float var = wsum(dv * dv) * (1.f / 64.f);
    float o = dv * (1.f / sqrtf(var + EPSV)) * lnfg[lane] + lnfb[lane];
    ushort_t h = f2b(o);
    Eh[b * 64 + lane] = h;
    El[b * 64 + lane] = f2b(o - b2f(h));
  }
}

// --------------------------------------------------------------- scoring ---
// R16 kernel: contiguous 256B NT stores (write-allocate elided).
#define LOADA(DH, DL, c) { int er = (c)*64 + w*16 + li;                 \
  DH[0] = *(const short8*)&Eh[er*64 + g*8];                             \
  DH[1] = *(const short8*)&Eh[er*64 + 32 + g*8];                        \
  DL[0] = *(const short8*)&El[er*64 + g*8];                             \
  DL[1] = *(const short8*)&El[er*64 + 32 + g*8]; }

#define CHUNK(c, CAh, CAl, NAh, NAl, PF) {                              \
  if (PF) LOADA(NAh, NAl, (c)+1);                                       \
  f32x4 acc[8];                                                         \
  _Pragma("unroll") for (int nt = 0; nt < 8; ++nt) acc[nt] = (f32x4)(0.f); \
  _Pragma("unroll") for (int kc = 0; kc < 2; ++kc){                     \
    _Pragma("unroll") for (int nt = 0; nt < 8; ++nt){                   \
      short8 bh = TB[nt*2 + kc][lane];                                  \
      short8 bl = TB[16 + nt*2 + kc][lane];                             \
      acc[nt] = __builtin_amdgcn_mfma_f32_16x16x32_bf16(CAh[kc], bh, acc[nt], 0, 0, 0); \
      acc[nt] = __builtin_amdgcn_mfma_f32_16x16x32_bf16(CAh[kc], bl, acc[nt], 0, 0, 0); \
      acc[nt] = __builtin_amdgcn_mfma_f32_16x16x32_bf16(CAl[kc], bh, acc[nt], 0, 0, 0); \
    }}                                                                  \
  _Pragma("unroll") for (int nt = 0; nt < 8; ++nt)                      \
    _Pragma("unroll") for (int r = 0; r < 4; ++r)                       \
      TT[w][g*4 + r][nt*16 + li] = acc[nt][r];                          \
  asm volatile("s_waitcnt lgkmcnt(0)" ::: "memory");                    \
  __builtin_amdgcn_sched_barrier(0);                                    \
  _Pragma("unroll") for (int k = 0; k < 4; ++k){                        \
    int rr = 4*k + g;                                                   \
    size_t rb = (size_t)((c)*64 + w*16 + rr) * NITEMS;                  \
    _Pragma("unroll") for (int h2 = 0; h2 < 2; ++h2){                   \
      int cidx = (h2*16 + li) * 4;                                      \
      int col = i0 + cidx;                                              \
      if (col < NITEMS){                                                \
        f32x4 v = *(const f32x4*)&TT[w][rr][cidx];                      \
        __builtin_nontemporal_store(v, (f32x4*)&out[rb + col]);         \
      }                                                                 \
    }}                                                                  \
  __builtin_amdgcn_sched_barrier(0); }

__global__ __launch_bounds__(256) void k_score(
    const ushort_t* __restrict__ Eh, const ushort_t* __restrict__ El,
    const float* __restrict__ T, float* __restrict__ out){
  __shared__ short8 TB[32][64];     // 32 KB: frag-ordered T tile (hi/lo)
  __shared__ float TT[4][16][132];  // 33 KB: per-wave transpose tiles
  const int t = threadIdx.x, lane = t & 63, w = t >> 6;  // 4 waves
  const int li = lane & 15, g = lane >> 4;
  const int i0 = blockIdx.x * 128;

  // ---- stage T tile (128 rows) into LDS fragment order, hi/lo bf16 ----
#pragma unroll
  for (int i = 0; i < 8; ++i){
    int e4 = t + 256 * i;            // [128 rows][16 float4-cols]
    int r = e4 >> 4, c4 = e4 & 15;
    int gi = i0 + r;
    float4 v = make_float4(0.f, 0.f, 0.f, 0.f);
    if (gi < NITEMS) v = ((const float4*)(T + (size_t)gi * 64))[c4];
    int nt = r >> 4, li2 = r & 15;
    int kc = c4 >> 3, g2 = (c4 >> 1) & 3, j0 = (c4 & 1) * 4;
    float f[4] = {v.x, v.y, v.z, v.w};
    u64_t ph = 0, pl = 0;
#pragma unroll
    for (int j = 0; j < 4; ++j){
      ushort_t hh = f2b(f[j]);
      ushort_t ll = f2b(f[j] - b2f(hh));
      ph |= (u64_t)hh << (16*j);
      pl |= (u64_t)ll << (16*j);
    }
    *(u64_t*)((ushort_t*)&TB[nt*2 + kc][g2*16 + li2] + j0) = ph;
    *(u64_t*)((ushort_t*)&TB[16 + nt*2 + kc][g2*16 + li2] + j0) = pl;
  }
  __syncthreads();

  // ---- 8 batch chunks, A double-buffered ----
  short8 Ah0[2], Al0[2], Ah1[2], Al1[2];
  LOADA(Ah0, Al0, 0);
  CHUNK(0, Ah0, Al0, Ah1, Al1, 1)
  CHUNK(1, Ah1, Al1, Ah0, Al0, 1)
  CHUNK(2, Ah0, Al0, Ah1, Al1, 1)
  CHUNK(3, Ah1, Al1, Ah0, Al0, 1)
  CHUNK(4, Ah0, Al0, Ah1, Al1, 1)
  CHUNK(5, Ah1, Al1, Ah0, Al0, 1)
  CHUNK(6, Ah0, Al0, Ah1, Al1, 1)
  CHUNK(7, Ah1, Al1, Ah0, Al0, 0)
}

// ----------------------------------------------------------------- launch --
extern "C" void kernel_launch(void* const* d_in, const int* in_sizes, int n_in,
                              void* d_out, int out_size, void* d_ws, size_t ws_size,
                              hipStream_t stream){
  const int*   ids      = (const int*)  d_in[0];
  const float* item_emb = (const float*)d_in[1];
  const float* pos_emb  = (const float*)d_in[2];
  const float* ln1g     = (const float*)d_in[3];
  const float* ln1b     = (const float*)d_in[4];
  const float* Wq       = (const float*)d_in[5];
  const float* bq       = (const float*)d_in[6];
  const float* Wk       = (const float*)d_in[7];
  const float* bk       = (const float*)d_in[8];
  const float* Wv       = (const float*)d_in[9];
  const float* bv       = (const float*)d_in[10];
  const float* ln2g     = (const float*)d_in[11];
  const float* ln2b     = (const float*)d_in[12];
  const float* W1       = (const float*)d_in[13];
  const float* b1       = (const float*)d_in[14];
  const float* W2       = (const float*)d_in[15];
  const float* b2       = (const float*)d_in[16];
  const float* lnfg     = (const float*)d_in[17];
  const float* lnfb     = (const float*)d_in[18];
  const float* items    = (const float*)d_in[19];
  float* out = (float*)d_out;

  ushort_t* Ehp = (ushort_t*)d_ws;                         // 64 KB
  ushort_t* Elp = Ehp + 512 * 64;                          // 64 KB
  short8*   Wp  = (short8*)((char*)d_ws + (256u << 10));   // 160 KB

  k_packw<<<10, 512, 0, stream>>>(Wq, Wk, Wv, W1, W2, Wp);
  k_layers<<<Bsz, 512, 0, stream>>>(ids, item_emb, pos_emb,
      ln1g, ln1b, Wp, bq, bk, bv,
      ln2g, ln2b, b1, b2, lnfg, lnfb, Ehp, Elp);
  k_score<<<1563, 256, 0, stream>>>(Ehp, Elp, items, out);
}